// Round 3
// baseline (230.908 us; speedup 1.0000x reference)
//
#include <hip/hip_runtime.h>
#include <hip/hip_bf16.h>

// out[b, i*E + j] = x[b, i] * W[i, j]
// B=8192, L=100, E=64 -> 209.7 MB fp32 output, write-streaming bound.
//
// Round-6: STRUCTURAL change of the store mapping. Rounds 0-5 used
// "thread owns a fixed column, strides the batch": each wave's stores jump
// 6.4 MB apart, and with only 32 stores/wave all 6400 waves dump their
// entire scattered streams at launch -> instantaneous write front is ~1 KB
// islands scattered across the whole 209.7 MB. Measured ~79-84 us (~2.6
// TB/s), 2.5x off the fill's 6.3-6.6 TB/s on the same buffer. Decoupling
// loads (round-5) was NEUTRAL -> the store pattern is the suspect.
//
// Both proven 6.3+ TB/s writers here (rocclr fill, m13 grid-stride copy)
// share one property ours lacked: a LINEARLY SWEEPING write window.
// So: canonical grid-stride copy shape. 2048 blocks x 256 threads;
// vec4 index g = bid*256+tid + it*524288; 25 iterations cover all
// 13,107,200 vec4s exactly. Each iteration = one contiguous 8 MB window,
// windows advance in address order.
//
// Per iteration: row = g/1600 (magic-mul), col = g%1600;
//   x[row, col>>4]  - 4 B load, 16 lanes share a value, sweeps 3.3 MB hot
//   W[col]          - 16 B load, 25.6 KB table, L1-resident after warmup
//   nt-store 16 B   - contiguous 1 KB per wave, 4 KB per block, 8 MB per
//                     grid-iteration
// m13 (6.29 TB/s copy) proves interleaved load+store at full occupancy
// sustains the write ceiling; VGPR kept low for 8 blocks/CU.

#define LENGTH 100
#define EMBED 64
#define BATCH 8192
#define NV4 (BATCH * LENGTH * EMBED / 4)   // 13,107,200 vec4 outputs
#define TPB 256
#define NBLK 2048
#define GSTRIDE (TPB * NBLK)               // 524,288 vec4 per grid-iteration
#define ITERS (NV4 / GSTRIDE)              // 25, exact

typedef float vfloat4 __attribute__((ext_vector_type(4)));

__global__ __launch_bounds__(TPB) void chemical_embedding_kernel(
    const float* __restrict__ x,
    const float* __restrict__ W,
    float* __restrict__ out)
{
    unsigned g = blockIdx.x * TPB + threadIdx.x;   // vec4 index
    const vfloat4* __restrict__ Wv = reinterpret_cast<const vfloat4*>(W);
    vfloat4* __restrict__ ov = reinterpret_cast<vfloat4*>(out);

#pragma unroll 5
    for (int it = 0; it < ITERS; ++it) {
        const unsigned row = g / 1600u;            // batch row (magic-mul)
        const unsigned col = g - row * 1600u;      // vec4 col in [0,1600)
        const float s = x[row * 100u + (col >> 4)];
        const vfloat4 v = s * Wv[col];
        __builtin_nontemporal_store(v, ov + g);    // contiguous 16B/lane
        g += GSTRIDE;
    }
}

extern "C" void kernel_launch(void* const* d_in, const int* in_sizes, int n_in,
                              void* d_out, int out_size, void* d_ws, size_t ws_size,
                              hipStream_t stream) {
    const float* x = (const float*)d_in[0];
    const float* W = (const float*)d_in[1];
    float* out = (float*)d_out;

    chemical_embedding_kernel<<<dim3(NBLK), dim3(TPB), 0, stream>>>(x, W, out);
}

// Round 4
// 205.053 us; speedup vs baseline: 1.1261x; 1.1261x over previous
//
#include <hip/hip_runtime.h>
#include <hip/hip_bf16.h>

// out[b, i*E + j] = x[b, i] * W[i, j]
// B=8192, L=100, E=64 -> 209.7 MB fp32 output, write-streaming bound.
//
// Round-7: revert to the proven round-0/R0 mapping (fixed column, stride
// the batch, 205.99 us) and test the last untested cell of the 2x2:
// PRELOADED x + NORMAL stores.
//   - R0  (interleaved loads + normal stores): 206 us total (~79 us kernel)
//   - R2  (preload + NT stores):               217 us (~84)   -> nt costs ~5
//   - R3  (per-iter loads + div/mod + nt + linear sweep): 231 us (~98)
// Falsified: vmcnt load/store interleave theory (R2 neutral-at-best) and
// DRAM write-scatter theory (R3's contiguous sweep REGRESSED). The 6.4 TB/s
// rocclr fill uses normal stores -> drop nontemporal, keep L2 write path.
//
// Structure: thread owns vec4 column r in [0,1600), loads its W vec4 once,
// burst-preloads its 32 x scalars (independent loads, static indices ->
// VGPRs), then runs a pure normal-store loop: 32 coalesced 16B stores,
// 6.4 MB apart (grid covers each 256-row slice contiguously).
// Grid (5, 256) x 320 threads = 6400 waves = 25 waves/CU.

#define LENGTH 100
#define EMBED 64
#define BATCH 8192
#define V4_PER_ROW (LENGTH * EMBED / 4)   // 1600
#define TPB 320                            // 5 waves; 5 blocks cover 1600 cols
#define BSLICES 256                        // batch slices
#define ITERS (BATCH / BSLICES)            // 32

typedef float vfloat4 __attribute__((ext_vector_type(4)));

__global__ __launch_bounds__(TPB) void chemical_embedding_kernel(
    const float* __restrict__ x,
    const float* __restrict__ W,
    float* __restrict__ out)
{
    const int r = blockIdx.x * TPB + threadIdx.x;   // vec4 column, [0,1600)
    const int i = r >> 4;                            // L index (E/4 = 16 vec4/i)

    // Loop-invariant: this thread's W fragment, loaded once.
    const vfloat4 w = reinterpret_cast<const vfloat4*>(W)[r];

    const int b0 = blockIdx.y;                       // starting batch row
    const float* __restrict__ xp = x + b0 * LENGTH + i;

    // ---- Phase 1: burst-load all 32 x scalars (independent, in flight
    // together; static indices keep s[] in VGPRs, ~40 total). ----
    float s[ITERS];
#pragma unroll
    for (int it = 0; it < ITERS; ++it)
        s[it] = xp[it * (BSLICES * LENGTH)];

    // ---- Phase 2: pure store stream, NORMAL stores (L2 write path, like
    // the 6.4 TB/s fill kernel). ----
    vfloat4* __restrict__ op =
        reinterpret_cast<vfloat4*>(out) + (size_t)b0 * V4_PER_ROW + r;
    const int ostep = BSLICES * V4_PER_ROW;          // out bump per slice

#pragma unroll
    for (int it = 0; it < ITERS; ++it) {
        *op = s[it] * w;                             // coalesced 16B store
        op += ostep;
    }
}

extern "C" void kernel_launch(void* const* d_in, const int* in_sizes, int n_in,
                              void* d_out, int out_size, void* d_ws, size_t ws_size,
                              hipStream_t stream) {
    const float* x = (const float*)d_in[0];
    const float* W = (const float*)d_in[1];
    float* out = (float*)d_out;

    dim3 grid(V4_PER_ROW / TPB, BSLICES);            // (5, 256) = 1280 blocks
    chemical_embedding_kernel<<<grid, TPB, 0, stream>>>(x, W, out);
}